// Round 7
// baseline (263.869 us; speedup 1.0000x reference)
//
#include <hip/hip_runtime.h>

// BitLinear: LN (no affine) -> global absmax int8 quant -> q @ sign(W-mean(W))^T
//   -> * (maxval/128 * mean|W|) + bias
// x: [4,2048,2048] f32 -> M=8192,K=2048 ; W: [8192,2048] -> N=8192 ; out f32 [8192,8192]

using i32x4 = __attribute__((ext_vector_type(4))) int;
using i32x16 = __attribute__((ext_vector_type(16))) int;

typedef const __attribute__((address_space(1))) void cg_void;
typedef __attribute__((address_space(3))) void lds_void;

#define K_DIM 2048
#define N_DIM 8192
#define M_DIM 8192
#define NELEM_W 16777216   // 8192*2048

// ws layout: scal@0 ([0]=absmax f32, [1]=wmean, [2]=beta); part@1024; mu@32768;
//            rstd@65536; rowmax@98304; q@131072; wq@131072+16M

// ---- fused pass1: W sum/abs-sum partials (blocks 0..1023) + LN stats (1024..9215) ----
__global__ __launch_bounds__(256) void pass1(const float* __restrict__ x,
                                             const float4* __restrict__ w4,
                                             float* __restrict__ mu_arr,
                                             float* __restrict__ rstd_arr,
                                             float* __restrict__ rowmax,
                                             double2* __restrict__ part) {
    __shared__ double sbd[8];
    __shared__ float sb1[4];
    __shared__ float sb2[8];
    const int bid = blockIdx.x, t = threadIdx.x;
    const int lane = t & 63, wv = t >> 6;
    if (bid < 1024) {
        double s = 0.0, a = 0.0;
        for (int i = bid * 256 + t; i < NELEM_W / 4; i += 1024 * 256) {
            float4 v = w4[i];
            s += (double)v.x + (double)v.y + (double)v.z + (double)v.w;
            a += fabs((double)v.x) + fabs((double)v.y) + fabs((double)v.z) + fabs((double)v.w);
        }
        for (int o = 32; o; o >>= 1) { s += __shfl_xor(s, o); a += __shfl_xor(a, o); }
        if (lane == 0) { sbd[wv] = s; sbd[4 + wv] = a; }
        __syncthreads();
        if (t == 0) {
            double2 r;
            r.x = sbd[0] + sbd[1] + sbd[2] + sbd[3];
            r.y = sbd[4] + sbd[5] + sbd[6] + sbd[7];
            part[bid] = r;
        }
    } else {
        const int row = bid - 1024;
        const float4* xr = (const float4*)x + (size_t)row * 512;
        float4 v0 = xr[t], v1 = xr[t + 256];
        float s = v0.x + v0.y + v0.z + v0.w + v1.x + v1.y + v1.z + v1.w;
        for (int o = 32; o; o >>= 1) s += __shfl_xor(s, o);
        if (lane == 0) sb1[wv] = s;
        __syncthreads();
        float mu = (sb1[0] + sb1[1] + sb1[2] + sb1[3]) * (1.0f / 2048.0f);
        float ssq = 0.f, md = 0.f, d;
        d = v0.x - mu; ssq += d * d; md = fmaxf(md, fabsf(d));
        d = v0.y - mu; ssq += d * d; md = fmaxf(md, fabsf(d));
        d = v0.z - mu; ssq += d * d; md = fmaxf(md, fabsf(d));
        d = v0.w - mu; ssq += d * d; md = fmaxf(md, fabsf(d));
        d = v1.x - mu; ssq += d * d; md = fmaxf(md, fabsf(d));
        d = v1.y - mu; ssq += d * d; md = fmaxf(md, fabsf(d));
        d = v1.z - mu; ssq += d * d; md = fmaxf(md, fabsf(d));
        d = v1.w - mu; ssq += d * d; md = fmaxf(md, fabsf(d));
        for (int o = 32; o; o >>= 1) {
            ssq += __shfl_xor(ssq, o);
            md = fmaxf(md, __shfl_xor(md, o));
        }
        if (lane == 0) { sb2[wv] = ssq; sb2[4 + wv] = md; }
        __syncthreads();
        if (t == 0) {
            float var = (sb2[0] + sb2[1] + sb2[2] + sb2[3]) * (1.0f / 2048.0f);
            float rstd = 1.0f / sqrtf(var + 1e-5f);
            mu_arr[row] = mu;
            rstd_arr[row] = rstd;
            rowmax[row] = fmaxf(fmaxf(sb2[4], sb2[5]), fmaxf(sb2[6], sb2[7])) * rstd;
        }
    }
}

// ---- wred2: finalize wmean/beta + global absmax ----
__global__ __launch_bounds__(256) void wred2(const double2* __restrict__ part,
                                             const float* __restrict__ rowmax,
                                             unsigned* __restrict__ scal) {
    double s = 0.0, a = 0.0;
    float m = 0.f;
    const int t = threadIdx.x, lane = t & 63, wv = t >> 6;
    for (int i = t; i < 1024; i += 256) { double2 p = part[i]; s += p.x; a += p.y; }
    for (int i = t; i < 8192; i += 256) m = fmaxf(m, rowmax[i]);
    for (int o = 32; o; o >>= 1) {
        s += __shfl_xor(s, o); a += __shfl_xor(a, o);
        m = fmaxf(m, __shfl_xor(m, o));
    }
    __shared__ double sbd[8];
    __shared__ float sbm[4];
    if (lane == 0) { sbd[wv] = s; sbd[4 + wv] = a; sbm[wv] = m; }
    __syncthreads();
    if (t == 0) {
        double st = sbd[0] + sbd[1] + sbd[2] + sbd[3];
        double at = sbd[4] + sbd[5] + sbd[6] + sbd[7];
        ((float*)scal)[0] = fmaxf(fmaxf(sbm[0], sbm[1]), fmaxf(sbm[2], sbm[3]));
        ((float*)scal)[1] = (float)(st / (double)NELEM_W);  // wmean
        ((float*)scal)[2] = (float)(at / (double)NELEM_W);  // beta
    }
}

// ---- fused pass2: quant_w (blocks 0..1023) + quant_x (1024..9215) ----
__device__ __forceinline__ int sgn8(float d) { return (d > 0.f) ? 1 : ((d < 0.f) ? -1 : 0); }

__global__ __launch_bounds__(256) void pass2(const float* __restrict__ x,
                                             const float4* __restrict__ w4,
                                             const float* __restrict__ mu_arr,
                                             const float* __restrict__ rstd_arr,
                                             const unsigned* __restrict__ scal,
                                             signed char* __restrict__ q,
                                             int4* __restrict__ wq4) {
    const int bid = blockIdx.x, t = threadIdx.x;
    if (bid < 1024) {
        float wm = ((const float*)scal)[1];
        for (int i = bid * 256 + t; i < NELEM_W / 16; i += 1024 * 256) {
            int words[4];
            #pragma unroll
            for (int jj = 0; jj < 4; ++jj) {
                float4 v = w4[i * 4 + jj];
                int b0 = sgn8(v.x - wm) & 255, b1 = sgn8(v.y - wm) & 255;
                int b2 = sgn8(v.z - wm) & 255, b3 = sgn8(v.w - wm) & 255;
                words[jj] = b0 | (b1 << 8) | (b2 << 16) | (b3 << 24);
            }
            wq4[i] = make_int4(words[0], words[1], words[2], words[3]);
        }
    } else {
        const int row = bid - 1024;
        float mu = mu_arr[row], rstd = rstd_arr[row];
        float s = 128.0f / ((const float*)scal)[0];
        const float4* xr = (const float4*)x + (size_t)row * 512;
        float4 v0 = xr[2 * t], v1 = xr[2 * t + 1];
        float xs[8] = {v0.x, v0.y, v0.z, v0.w, v1.x, v1.y, v1.z, v1.w};
        int b[8];
        #pragma unroll
        for (int j = 0; j < 8; ++j) {
            float norm = (xs[j] - mu) * rstd;
            int qi = (int)rintf(norm * s);   // half-even == jnp.round; +128 wraps via &255
            b[j] = qi & 255;
        }
        int w0 = b[0] | (b[1] << 8) | (b[2] << 16) | (b[3] << 24);
        int w1 = b[4] | (b[5] << 8) | (b[6] << 16) | (b[7] << 24);
        ((int2*)(q + (size_t)row * 2048))[t] = make_int2(w0, w1);
    }
}

// ---- int8 GEMM v7: r6 geometry + slot-permuted LDS layout (conflict-free @64B rows) ----
// 256x128 tile, BK=64, 8 waves (4Mx2N), per-wave 64x64 = 2x2 of 32x32, 48KB LDS,
// 2 blocks/CU. LDS mapping: addr(row,c16) = (row>>3)*512 + (c16*8 + ((row&7)^c16))*16.
// Bijective per 8-row group; any fragment read (fixed c16, rows varying) hits 8
// distinct bank-quads per 8-lane group. DMA dest stays wave-linear; the permutation
// is applied to the per-lane *global source* address (m173 pattern).
#define LD16(p) (*(const i32x4*)(p))
#define TILE_BYTES 24576   // A 16K + B 8K per buffer

#define STAGE(koff, sbase)                                                                  \
    do {                                                                                    \
        __builtin_amdgcn_global_load_lds((cg_void*)(gA + (koff)),                           \
            (lds_void*)(lds + (sbase) + w * 2048), 16, 0, 0);                               \
        __builtin_amdgcn_global_load_lds((cg_void*)(gA + 16 * K_DIM + (koff)),              \
            (lds_void*)(lds + (sbase) + w * 2048 + 1024), 16, 0, 0);                        \
        __builtin_amdgcn_global_load_lds((cg_void*)(gB + (koff)),                           \
            (lds_void*)(lds + (sbase) + 16384 + w * 1024), 16, 0, 0);                       \
    } while (0)

__global__ __launch_bounds__(512, 4) void gemm_i8(const signed char* __restrict__ A,
                                                  const signed char* __restrict__ B,
                                                  const float* __restrict__ bias,
                                                  const unsigned* __restrict__ scal,
                                                  float* __restrict__ C) {
    __shared__ alignas(16) char lds[49152];    // 2 x (A 16K + B 8K)
    const int t = threadIdx.x, w = t >> 6, lane = t & 63;

    // grid 2048 = 8 XCD x (4 m-panels x 64 n); A panel (512 KB) stays L2-hot per XCD.
    const int wg = blockIdx.x;
    const int xcd = wg & 7, idx = wg >> 3;
    const int bm = (xcd * 4 + (idx >> 6)) * 256;
    const int bn = (idx & 63) * 128;

    const int wr = w >> 1, wc = w & 1;         // wave grid 4M x 2N
    const int r32 = lane & 31, hi = lane >> 5; // 32x32 fragment coords

    // staging: wave-linear LDS dest (base + lane*16); lane's global source encodes the
    // slot permutation: grp-local row = (lane&7) ^ c16, c16 = (lane>>3)&3, grp = lane>>5
    const int sc16 = (lane >> 3) & 3;
    const int prow = (lane >> 5) * 8 + ((lane & 7) ^ sc16);
    const int pcol = sc16 * 16;
    const signed char* gA = A + (size_t)(bm + w * 32 + prow) * K_DIM + pcol;
    const signed char* gB = B + (size_t)(bn + w * 16 + prow) * K_DIM + pcol;

    // fragment reads: row = (wr*64|wc*64) + mb*32 + r32, c16 = kstep*2 + hi
    // addr = (row>>3)*512 + slot*16, slot = c16*8 + ((row&7)^c16)
    const char* aBase = lds + wr * 4096 + (r32 >> 3) * 512;
    const char* bBase = lds + 16384 + wc * 4096 + (r32 >> 3) * 512;
    const int c0 = hi;          // kstep 0 c16
    const int c1 = 2 + hi;      // kstep 1 c16
    const int soff0 = (c0 * 8 + ((r32 & 7) ^ c0)) * 16;
    const int soff1 = (c1 * 8 + ((r32 & 7) ^ c1)) * 16;

    const float scale = (((const float*)scal)[0] * (1.0f / 128.0f)) * ((const float*)scal)[2];

    i32x16 acc[2][2] = {};
    i32x4 a0[2], a1[2], b0[2], b1[2];

    STAGE(0, 0);   // prologue: tile 0 -> buf0 (3 loads in flight)

    #pragma unroll 2
    for (int kt = 0; kt < 32; ++kt) {
        const int c = (kt & 1) * TILE_BYTES;
        if (kt < 31) {
            STAGE((kt + 1) * 64, ((kt + 1) & 1) * TILE_BYTES);
            asm volatile("s_waitcnt vmcnt(3)" ::: "memory");  // this tile's 3 landed
        } else {
            asm volatile("s_waitcnt vmcnt(0)" ::: "memory");
        }
        __builtin_amdgcn_s_barrier();          // buf c ready

        #pragma unroll
        for (int mb = 0; mb < 2; ++mb) a0[mb] = LD16(aBase + c + mb * 2048 + soff0);
        #pragma unroll
        for (int nb = 0; nb < 2; ++nb) b0[nb] = LD16(bBase + c + nb * 2048 + soff0);
        #pragma unroll
        for (int mb = 0; mb < 2; ++mb) a1[mb] = LD16(aBase + c + mb * 2048 + soff1);
        #pragma unroll
        for (int nb = 0; nb < 2; ++nb) b1[nb] = LD16(bBase + c + nb * 2048 + soff1);
        __builtin_amdgcn_s_setprio(1);
        #pragma unroll
        for (int mb = 0; mb < 2; ++mb)
            #pragma unroll
            for (int nb = 0; nb < 2; ++nb)
                acc[mb][nb] = __builtin_amdgcn_mfma_i32_32x32x32_i8(a0[mb], b0[nb],
                                                                    acc[mb][nb], 0, 0, 0);
        #pragma unroll
        for (int mb = 0; mb < 2; ++mb)
            #pragma unroll
            for (int nb = 0; nb < 2; ++nb)
                acc[mb][nb] = __builtin_amdgcn_mfma_i32_32x32x32_i8(a1[mb], b1[nb],
                                                                    acc[mb][nb], 0, 0, 0);
        __builtin_amdgcn_s_setprio(0);
        __builtin_amdgcn_s_barrier();          // all waves done reading buf c
    }

    const int colbase = bn + wc * 64;
    float bi[2];
    #pragma unroll
    for (int nb = 0; nb < 2; ++nb) bi[nb] = bias[colbase + nb * 32 + r32];
    #pragma unroll
    for (int mb = 0; mb < 2; ++mb) {
        #pragma unroll
        for (int nb = 0; nb < 2; ++nb) {
            #pragma unroll
            for (int r = 0; r < 16; ++r) {
                // C/D 32x32: col = lane&31, row = (r&3) + 8*(r>>2) + 4*(lane>>5)
                int row = bm + wr * 64 + mb * 32 + (r & 3) + 8 * (r >> 2) + 4 * hi;
                int col = colbase + nb * 32 + r32;
                C[(size_t)row * N_DIM + col] = (float)acc[mb][nb][r] * scale + bi[nb];
            }
        }
    }
}

extern "C" void kernel_launch(void* const* d_in, const int* in_sizes, int n_in,
                              void* d_out, int out_size, void* d_ws, size_t ws_size,
                              hipStream_t stream) {
    const float* x = (const float*)d_in[0];
    const float* wts = (const float*)d_in[1];
    const float* bias = (const float*)d_in[2];
    float* out = (float*)d_out;

    char* ws = (char*)d_ws;
    unsigned* scal = (unsigned*)ws;                       // 64 B
    double2* part = (double2*)(ws + 1024);                // 16 KB
    float* mu = (float*)(ws + 32768);                     // 32 KB
    float* rstd = (float*)(ws + 65536);                   // 32 KB
    float* rowmax = (float*)(ws + 98304);                 // 32 KB
    signed char* q = (signed char*)(ws + 131072);         // 16 MB
    signed char* wq = (signed char*)(ws + 131072 + 16777216);  // 16 MB

    hipLaunchKernelGGL(pass1, dim3(9216), dim3(256), 0, stream,
                       x, (const float4*)wts, mu, rstd, rowmax, part);
    hipLaunchKernelGGL(wred2, dim3(1), dim3(256), 0, stream, part, rowmax, scal);
    hipLaunchKernelGGL(pass2, dim3(9216), dim3(256), 0, stream,
                       x, (const float4*)wts, mu, rstd, scal, q, (int4*)wq);
    hipLaunchKernelGGL(gemm_i8, dim3(2048), dim3(512), 0, stream,
                       q, wq, bias, scal, out);
}

// Round 8
// 226.913 us; speedup vs baseline: 1.1629x; 1.1629x over previous
//
#include <hip/hip_runtime.h>

// BitLinear: LN (no affine) -> global absmax int8 quant -> q @ sign(W-mean(W))^T
//   -> * (maxval/128 * mean|W|) + bias
// x: [4,2048,2048] f32 -> M=8192,K=2048 ; W: [8192,2048] -> N=8192 ; out f32 [8192,8192]

using i32x4 = __attribute__((ext_vector_type(4))) int;
using i32x16 = __attribute__((ext_vector_type(16))) int;

typedef const __attribute__((address_space(1))) void cg_void;
typedef __attribute__((address_space(3))) void lds_void;

#define K_DIM 2048
#define N_DIM 8192
#define M_DIM 8192
#define NELEM_W 16777216   // 8192*2048

// ws layout: scal@0 ([0]=absmax f32, [1]=wmean, [2]=beta); part@1024; mu@32768;
//            rstd@65536; rowmax@98304; q@131072; wq@131072+16M

// ---- fused pass1: W sum/abs-sum partials (blocks 0..1023) + LN stats (1024..9215) ----
__global__ __launch_bounds__(256) void pass1(const float* __restrict__ x,
                                             const float4* __restrict__ w4,
                                             float* __restrict__ mu_arr,
                                             float* __restrict__ rstd_arr,
                                             float* __restrict__ rowmax,
                                             double2* __restrict__ part) {
    __shared__ double sbd[8];
    __shared__ float sb1[4];
    __shared__ float sb2[8];
    const int bid = blockIdx.x, t = threadIdx.x;
    const int lane = t & 63, wv = t >> 6;
    if (bid < 1024) {
        double s = 0.0, a = 0.0;
        for (int i = bid * 256 + t; i < NELEM_W / 4; i += 1024 * 256) {
            float4 v = w4[i];
            s += (double)v.x + (double)v.y + (double)v.z + (double)v.w;
            a += fabs((double)v.x) + fabs((double)v.y) + fabs((double)v.z) + fabs((double)v.w);
        }
        for (int o = 32; o; o >>= 1) { s += __shfl_xor(s, o); a += __shfl_xor(a, o); }
        if (lane == 0) { sbd[wv] = s; sbd[4 + wv] = a; }
        __syncthreads();
        if (t == 0) {
            double2 r;
            r.x = sbd[0] + sbd[1] + sbd[2] + sbd[3];
            r.y = sbd[4] + sbd[5] + sbd[6] + sbd[7];
            part[bid] = r;
        }
    } else {
        const int row = bid - 1024;
        const float4* xr = (const float4*)x + (size_t)row * 512;
        float4 v0 = xr[t], v1 = xr[t + 256];
        float s = v0.x + v0.y + v0.z + v0.w + v1.x + v1.y + v1.z + v1.w;
        for (int o = 32; o; o >>= 1) s += __shfl_xor(s, o);
        if (lane == 0) sb1[wv] = s;
        __syncthreads();
        float mu = (sb1[0] + sb1[1] + sb1[2] + sb1[3]) * (1.0f / 2048.0f);
        float ssq = 0.f, md = 0.f, d;
        d = v0.x - mu; ssq += d * d; md = fmaxf(md, fabsf(d));
        d = v0.y - mu; ssq += d * d; md = fmaxf(md, fabsf(d));
        d = v0.z - mu; ssq += d * d; md = fmaxf(md, fabsf(d));
        d = v0.w - mu; ssq += d * d; md = fmaxf(md, fabsf(d));
        d = v1.x - mu; ssq += d * d; md = fmaxf(md, fabsf(d));
        d = v1.y - mu; ssq += d * d; md = fmaxf(md, fabsf(d));
        d = v1.z - mu; ssq += d * d; md = fmaxf(md, fabsf(d));
        d = v1.w - mu; ssq += d * d; md = fmaxf(md, fabsf(d));
        for (int o = 32; o; o >>= 1) {
            ssq += __shfl_xor(ssq, o);
            md = fmaxf(md, __shfl_xor(md, o));
        }
        if (lane == 0) { sb2[wv] = ssq; sb2[4 + wv] = md; }
        __syncthreads();
        if (t == 0) {
            float var = (sb2[0] + sb2[1] + sb2[2] + sb2[3]) * (1.0f / 2048.0f);
            float rstd = 1.0f / sqrtf(var + 1e-5f);
            mu_arr[row] = mu;
            rstd_arr[row] = rstd;
            rowmax[row] = fmaxf(fmaxf(sb2[4], sb2[5]), fmaxf(sb2[6], sb2[7])) * rstd;
        }
    }
}

// ---- wred2: finalize wmean/beta + global absmax ----
__global__ __launch_bounds__(256) void wred2(const double2* __restrict__ part,
                                             const float* __restrict__ rowmax,
                                             unsigned* __restrict__ scal) {
    double s = 0.0, a = 0.0;
    float m = 0.f;
    const int t = threadIdx.x, lane = t & 63, wv = t >> 6;
    for (int i = t; i < 1024; i += 256) { double2 p = part[i]; s += p.x; a += p.y; }
    for (int i = t; i < 8192; i += 256) m = fmaxf(m, rowmax[i]);
    for (int o = 32; o; o >>= 1) {
        s += __shfl_xor(s, o); a += __shfl_xor(a, o);
        m = fmaxf(m, __shfl_xor(m, o));
    }
    __shared__ double sbd[8];
    __shared__ float sbm[4];
    if (lane == 0) { sbd[wv] = s; sbd[4 + wv] = a; sbm[wv] = m; }
    __syncthreads();
    if (t == 0) {
        double st = sbd[0] + sbd[1] + sbd[2] + sbd[3];
        double at = sbd[4] + sbd[5] + sbd[6] + sbd[7];
        ((float*)scal)[0] = fmaxf(fmaxf(sbm[0], sbm[1]), fmaxf(sbm[2], sbm[3]));
        ((float*)scal)[1] = (float)(st / (double)NELEM_W);  // wmean
        ((float*)scal)[2] = (float)(at / (double)NELEM_W);  // beta
    }
}

// ---- fused pass2: quant_w (blocks 0..1023) + quant_x (1024..9215) ----
__device__ __forceinline__ int sgn8(float d) { return (d > 0.f) ? 1 : ((d < 0.f) ? -1 : 0); }

__global__ __launch_bounds__(256) void pass2(const float* __restrict__ x,
                                             const float4* __restrict__ w4,
                                             const float* __restrict__ mu_arr,
                                             const float* __restrict__ rstd_arr,
                                             const unsigned* __restrict__ scal,
                                             signed char* __restrict__ q,
                                             int4* __restrict__ wq4) {
    const int bid = blockIdx.x, t = threadIdx.x;
    if (bid < 1024) {
        float wm = ((const float*)scal)[1];
        for (int i = bid * 256 + t; i < NELEM_W / 16; i += 1024 * 256) {
            int words[4];
            #pragma unroll
            for (int jj = 0; jj < 4; ++jj) {
                float4 v = w4[i * 4 + jj];
                int b0 = sgn8(v.x - wm) & 255, b1 = sgn8(v.y - wm) & 255;
                int b2 = sgn8(v.z - wm) & 255, b3 = sgn8(v.w - wm) & 255;
                words[jj] = b0 | (b1 << 8) | (b2 << 16) | (b3 << 24);
            }
            wq4[i] = make_int4(words[0], words[1], words[2], words[3]);
        }
    } else {
        const int row = bid - 1024;
        float mu = mu_arr[row], rstd = rstd_arr[row];
        float s = 128.0f / ((const float*)scal)[0];
        const float4* xr = (const float4*)x + (size_t)row * 512;
        float4 v0 = xr[2 * t], v1 = xr[2 * t + 1];
        float xs[8] = {v0.x, v0.y, v0.z, v0.w, v1.x, v1.y, v1.z, v1.w};
        int b[8];
        #pragma unroll
        for (int j = 0; j < 8; ++j) {
            float norm = (xs[j] - mu) * rstd;
            int qi = (int)rintf(norm * s);   // half-even == jnp.round; +128 wraps via &255
            b[j] = qi & 255;
        }
        int w0 = b[0] | (b[1] << 8) | (b[2] << 16) | (b[3] << 24);
        int w1 = b[4] | (b[5] << 8) | (b[6] << 16) | (b[7] << 24);
        ((int2*)(q + (size_t)row * 2048))[t] = make_int2(w0, w1);
    }
}

// ---- int8 GEMM v8: r6 geometry + PACKED 128B-row LDS (r2-proven 0-conflict swizzle) ----
// 256x128 tile, BK=64, 8 waves (4Mx2N), 48KB LDS, 2 blocks/CU, 32x32x32 MFMA.
// LDS packs tile-row pairs into 128B rows: A rows (r, r+128) -> LDS row r&127;
// B rows (r, r+64) -> LDS row r&63. 16B slot = (half*4 + c16) ^ (row&7)  [full 8-slot
// XOR, the r2-measured zero-conflict structure]. DMA dest stays wave-linear; the
// inverse permutation goes into the per-lane GLOBAL source, which remains coalesced:
// every 8 lanes read two 64B segments (same as r6; r7's scatter is avoided).
#define LD16(p) (*(const i32x4*)(p))
#define TILE_BYTES 24576   // A 16K + B 8K per buffer

#define STAGE(koff, sbase)                                                                  \
    do {                                                                                    \
        __builtin_amdgcn_global_load_lds((cg_void*)(gA + (koff)),                           \
            (lds_void*)(lds + (sbase) + w * 2048), 16, 0, 0);                               \
        __builtin_amdgcn_global_load_lds((cg_void*)(gA + 8 * K_DIM + (koff)),               \
            (lds_void*)(lds + (sbase) + w * 2048 + 1024), 16, 0, 0);                        \
        __builtin_amdgcn_global_load_lds((cg_void*)(gB + (koff)),                           \
            (lds_void*)(lds + (sbase) + 16384 + w * 1024), 16, 0, 0);                       \
    } while (0)

__global__ __launch_bounds__(512, 4) void gemm_i8(const signed char* __restrict__ A,
                                                  const signed char* __restrict__ B,
                                                  const float* __restrict__ bias,
                                                  const unsigned* __restrict__ scal,
                                                  float* __restrict__ C) {
    __shared__ alignas(16) char lds[49152];    // 2 x (A 16K + B 8K)
    const int t = threadIdx.x, w = t >> 6, lane = t & 63;

    // grid 2048 = 8 XCD x (4 m-panels x 64 n); A panel (512 KB) stays L2-hot per XCD.
    const int wg = blockIdx.x;
    const int xcd = wg & 7, idx = wg >> 3;
    const int bm = (xcd * 4 + (idx >> 6)) * 256;
    const int bn = (idx & 63) * 128;

    const int wr = w >> 1, wc = w & 1;         // wave grid 4M x 2N
    const int r32 = lane & 31, hi = lane >> 5; // 32x32 fragment coords

    // ---- DMA source mapping (inverse of packed-swizzled layout) ----
    // linear LDS off o = chunkbase + lane*16 -> LDS row R = chunkrow + (lane>>3),
    // slot s = lane&7; unswizzled u = s ^ (R&7) = (lane&7)^(lane>>3);
    // tile row = R + rows_per_half*(u>>2); 16B col = u&3.
    const int uu = (lane & 7) ^ (lane >> 3);
    const int aRow = w * 16 + (lane >> 3) + ((uu >> 2) << 7);
    const int bRow = w * 8 + (lane >> 3) + ((uu >> 2) << 6);
    const int gcol = (uu & 3) << 4;
    const signed char* gA = A + (size_t)(bm + aRow) * K_DIM + gcol;
    const signed char* gB = B + (size_t)(bn + bRow) * K_DIM + gcol;

    // ---- fragment read addressing ----
    // A row = wr*64 + mb*32 + r32 (<256): LDS row = (wr&1)*64 + mb*32 + r32,
    //   half = wr>>1; slot = ((wr>>1)*4 + ks*2 + hi) ^ (r32&7)
    // B row = wc*64 + nb*32 + r32 (<128): LDS row = nb*32 + r32, half = wc;
    //   slot = (wc*4 + ks*2 + hi) ^ (r32&7)
    const char* aBase = lds + ((wr & 1) * 64 + r32) * 128;
    const char* bBase = lds + 16384 + r32 * 128;
    const int axr = r32 & 7;
    const int aS0 = ((((wr >> 1) << 2) + hi) ^ axr) << 4;        // A ks=0
    const int aS1 = ((((wr >> 1) << 2) + 2 + hi) ^ axr) << 4;    // A ks=1
    const int bS0 = (((wc << 2) + hi) ^ axr) << 4;               // B ks=0
    const int bS1 = (((wc << 2) + 2 + hi) ^ axr) << 4;           // B ks=1

    const float scale = (((const float*)scal)[0] * (1.0f / 128.0f)) * ((const float*)scal)[2];

    i32x16 acc[2][2] = {};
    i32x4 a0[2], a1[2], b0[2], b1[2];

    STAGE(0, 0);   // prologue: tile 0 -> buf0 (3 loads in flight)

    #pragma unroll 2
    for (int kt = 0; kt < 32; ++kt) {
        const int c = (kt & 1) * TILE_BYTES;
        if (kt < 31) {
            STAGE((kt + 1) * 64, ((kt + 1) & 1) * TILE_BYTES);
            asm volatile("s_waitcnt vmcnt(3)" ::: "memory");  // this tile's 3 landed
        } else {
            asm volatile("s_waitcnt vmcnt(0)" ::: "memory");
        }
        __builtin_amdgcn_s_barrier();          // buf c ready

        #pragma unroll
        for (int mb = 0; mb < 2; ++mb) a0[mb] = LD16(aBase + c + mb * 4096 + aS0);
        #pragma unroll
        for (int nb = 0; nb < 2; ++nb) b0[nb] = LD16(bBase + c + nb * 4096 + bS0);
        #pragma unroll
        for (int mb = 0; mb < 2; ++mb) a1[mb] = LD16(aBase + c + mb * 4096 + aS1);
        #pragma unroll
        for (int nb = 0; nb < 2; ++nb) b1[nb] = LD16(bBase + c + nb * 4096 + bS1);
        __builtin_amdgcn_s_setprio(1);
        #pragma unroll
        for (int mb = 0; mb < 2; ++mb)
            #pragma unroll
            for (int nb = 0; nb < 2; ++nb)
                acc[mb][nb] = __builtin_amdgcn_mfma_i32_32x32x32_i8(a0[mb], b0[nb],
                                                                    acc[mb][nb], 0, 0, 0);
        #pragma unroll
        for (int mb = 0; mb < 2; ++mb)
            #pragma unroll
            for (int nb = 0; nb < 2; ++nb)
                acc[mb][nb] = __builtin_amdgcn_mfma_i32_32x32x32_i8(a1[mb], b1[nb],
                                                                    acc[mb][nb], 0, 0, 0);
        __builtin_amdgcn_s_setprio(0);
        __builtin_amdgcn_s_barrier();          // all waves done reading buf c
    }

    const int colbase = bn + wc * 64;
    float bi[2];
    #pragma unroll
    for (int nb = 0; nb < 2; ++nb) bi[nb] = bias[colbase + nb * 32 + r32];
    #pragma unroll
    for (int mb = 0; mb < 2; ++mb) {
        #pragma unroll
        for (int nb = 0; nb < 2; ++nb) {
            #pragma unroll
            for (int r = 0; r < 16; ++r) {
                // C/D 32x32: col = lane&31, row = (r&3) + 8*(r>>2) + 4*(lane>>5)
                int row = bm + wr * 64 + mb * 32 + (r & 3) + 8 * (r >> 2) + 4 * hi;
                int col = colbase + nb * 32 + r32;
                C[(size_t)row * N_DIM + col] = (float)acc[mb][nb][r] * scale + bi[nb];
            }
        }
    }
}

extern "C" void kernel_launch(void* const* d_in, const int* in_sizes, int n_in,
                              void* d_out, int out_size, void* d_ws, size_t ws_size,
                              hipStream_t stream) {
    const float* x = (const float*)d_in[0];
    const float* wts = (const float*)d_in[1];
    const float* bias = (const float*)d_in[2];
    float* out = (float*)d_out;

    char* ws = (char*)d_ws;
    unsigned* scal = (unsigned*)ws;                       // 64 B
    double2* part = (double2*)(ws + 1024);                // 16 KB
    float* mu = (float*)(ws + 32768);                     // 32 KB
    float* rstd = (float*)(ws + 65536);                   // 32 KB
    float* rowmax = (float*)(ws + 98304);                 // 32 KB
    signed char* q = (signed char*)(ws + 131072);         // 16 MB
    signed char* wq = (signed char*)(ws + 131072 + 16777216);  // 16 MB

    hipLaunchKernelGGL(pass1, dim3(9216), dim3(256), 0, stream,
                       x, (const float4*)wts, mu, rstd, rowmax, part);
    hipLaunchKernelGGL(wred2, dim3(1), dim3(256), 0, stream, part, rowmax, scal);
    hipLaunchKernelGGL(pass2, dim3(9216), dim3(256), 0, stream,
                       x, (const float4*)wts, mu, rstd, scal, q, (int4*)wq);
    hipLaunchKernelGGL(gemm_i8, dim3(2048), dim3(512), 0, stream,
                       q, wq, bias, scal, out);
}